// Round 8
// baseline (18864.890 us; speedup 1.0000x reference)
//
#include <hip/hip_runtime.h>
#include <hip/hip_bf16.h>

// Seq2seq GRU (2-layer enc T=192, 2-layer dec T=96), B=128, H=1024.
// Round 8: persistent v4. 96 blocks (32 i-tiles x 3 roles {L0, gi1, L1}),
// 512 thr = 8 waves = 8 m-tiles (Mtile=128, Ntile=32, full-K per wave, no
// LDS, no intra-block sync). Weights: plain cached loads -> L2-resident all
// steps (no fences/invalidation ever). Shared state (bf16 h, gi): sc1
// agent-scope relaxed atomics (L3-coherent). Private f32 state: normal.
// Barrier: 8 arrival counters (12 RMW each) + 1 leader wave + 8 release
// lines with sleep-paced pollers (no line hammering, no RMW ping-pong).

#define H 1024
#define G 3072
#define BB 128
#define TENC 192
#define TDEC 96
#define NBLK 96
#define NSTEP (TENC + 2 + TDEC + 2)   /* 194 + 98 = 292 */

typedef __attribute__((ext_vector_type(4))) float f32x4;
typedef __attribute__((ext_vector_type(8))) short bf16x8;

#define MFMA16(a, b, c) __builtin_amdgcn_mfma_f32_16x16x32_bf16(a, b, c, 0, 0, 0)

__device__ __forceinline__ float sigmoidf_(float x) {
    return 1.0f / (1.0f + __expf(-x));
}

__device__ __forceinline__ short f2bf_rne(float f) {
    union { float f; unsigned u; } v; v.f = f;
    unsigned r = v.u + 0x7fffu + ((v.u >> 16) & 1u);
    return (short)(r >> 16);
}

// 16B sc1 (agent/L3) load/store helpers
__device__ __forceinline__ bf16x8 ald16(const short* p) {
    const unsigned long long* q = (const unsigned long long*)p;
    unsigned long long a = __hip_atomic_load(q, __ATOMIC_RELAXED, __HIP_MEMORY_SCOPE_AGENT);
    unsigned long long b = __hip_atomic_load(q + 1, __ATOMIC_RELAXED, __HIP_MEMORY_SCOPE_AGENT);
    union { unsigned long long u[2]; bf16x8 v; } x;
    x.u[0] = a; x.u[1] = b;
    return x.v;
}
__device__ __forceinline__ f32x4 ald16f(const float* p) {
    const unsigned long long* q = (const unsigned long long*)p;
    unsigned long long a = __hip_atomic_load(q, __ATOMIC_RELAXED, __HIP_MEMORY_SCOPE_AGENT);
    unsigned long long b = __hip_atomic_load(q + 1, __ATOMIC_RELAXED, __HIP_MEMORY_SCOPE_AGENT);
    union { unsigned long long u[2]; f32x4 v; } x;
    x.u[0] = a; x.u[1] = b;
    return x.v;
}
__device__ __forceinline__ void ast16f(float* p, f32x4 v) {
    union { f32x4 f; unsigned long long u[2]; } x; x.f = v;
    __hip_atomic_store((unsigned long long*)p, x.u[0], __ATOMIC_RELAXED, __HIP_MEMORY_SCOPE_AGENT);
    __hip_atomic_store((unsigned long long*)p + 1, x.u[1], __ATOMIC_RELAXED, __HIP_MEMORY_SCOPE_AGENT);
}

__global__ __launch_bounds__(256) void k_f2bf(const float* __restrict__ in,
                                              short* __restrict__ out, int n) {
    for (int i = blockIdx.x * 256 + threadIdx.x; i < n; i += gridDim.x * 256)
        out[i] = f2bf_rne(in[i]);
}

// dec_in[b][t][c]: t==0 -> x_enc[b][191][c], else x_dec[b][t-1][c]
__global__ __launch_bounds__(256) void k_build_decin(const float* __restrict__ x_enc,
                                                     const float* __restrict__ x_dec,
                                                     short* __restrict__ out) {
    int i = blockIdx.x * 256 + threadIdx.x;
    if (i >= BB * TDEC * 32) return;
    int c = i & 31;
    int t = (i >> 5) % TDEC;
    int b = i / (TDEC * 32);
    float v = (t == 0) ? x_enc[(size_t)b * TENC * 32 + 191 * 32 + c]
                       : x_dec[(size_t)b * TDEC * 32 + (t - 1) * 32 + c];
    out[i] = f2bf_rne(v);
}

__global__ __launch_bounds__(512) void k_persist(
    const short* __restrict__ xencbf, const short* __restrict__ decinbf,
    const short* __restrict__ wih0e, const short* __restrict__ whh0e,
    const float* __restrict__ ebih0, const float* __restrict__ ebhh0,
    const short* __restrict__ wih1e, const short* __restrict__ whh1e,
    const float* __restrict__ ebih1, const float* __restrict__ ebhh1,
    const short* __restrict__ wih0d, const short* __restrict__ whh0d,
    const float* __restrict__ dbih0, const float* __restrict__ dbhh0,
    const short* __restrict__ wih1d, const short* __restrict__ whh1d,
    const float* __restrict__ dbih1, const float* __restrict__ dbhh1,
    short* __restrict__ y0r, float* __restrict__ pp0,
    short* __restrict__ hbf1, float* __restrict__ pp1,
    float* __restrict__ gibuf, float* __restrict__ y1,
    unsigned* __restrict__ barr, unsigned* __restrict__ rel)
{
    const int tid  = threadIdx.x;
    const int w    = tid >> 6;          // wave 0..7 = m-tile
    const int lane = tid & 63;
    const int lr   = lane & 15;
    const int kg   = lane >> 4;
    const int bid  = blockIdx.x;
    const int role = bid >> 5;          // 0:L0  1:gi1  2:L1
    const int i0   = (bid & 31) * 32;
    const int b0   = w * 16;
    const size_t HS  = (size_t)BB * H;
    const size_t GIS = (size_t)3 * BB * H;

    // hoist biases (roles 0 and 2): [enc/dec][cs]
    float bR[2][2], bZ[2][2], bGN[2][2], bHN[2][2];
    if (role != 1) {
        const float* bi[2] = { (role == 0) ? ebih0 : ebih1, (role == 0) ? dbih0 : dbih1 };
        const float* bh[2] = { (role == 0) ? ebhh0 : ebhh1, (role == 0) ? dbhh0 : dbhh1 };
        #pragma unroll
        for (int ph = 0; ph < 2; ++ph)
            #pragma unroll
            for (int cs = 0; cs < 2; ++cs) {
                int col = i0 + cs * 16 + lr;
                bR[ph][cs]  = bi[ph][col] + bh[ph][col];
                bZ[ph][cs]  = bi[ph][H + col] + bh[ph][H + col];
                bGN[ph][cs] = bi[ph][2 * H + col];
                bHN[ph][cs] = bh[ph][2 * H + col];
            }
    }

    for (int u = 0; u < NSTEP; ++u) {
        const bool enc = (u < TENC + 2);
        const int s = enc ? u : (u - (TENC + 2));
        const int T = enc ? TENC : TDEC;
        const int t = s - role;
        const int ph = enc ? 0 : 1;
        const bool act = (t >= 0) && (t < T);

        if (act) {
            const int rds = (t == 0) ? 1 : ((t - 1) & 1);
            const short* abase = (role == 0) ? (y0r + (size_t)rds * HS)
                               : (role == 1) ? (y0r + (size_t)(t & 1) * HS)
                                             : (hbf1 + (size_t)rds * HS);
            const short* ah = abase + ((size_t)(b0 + lr) << 10) + kg * 8;
            const short* wsel = (role == 0) ? (enc ? whh0e : whh0d)
                              : (role == 1) ? (enc ? wih1e : wih1d)
                                            : (enc ? whh1e : whh1d);
            const short* wb[6];
            #pragma unroll
            for (int cs = 0; cs < 2; ++cs)
                #pragma unroll
                for (int g = 0; g < 3; ++g)
                    wb[cs * 3 + g] = wsel + ((size_t)(g * H + i0 + cs * 16 + lr) << 10) + kg * 8;

            f32x4 acc[6];
            #pragma unroll
            for (int j = 0; j < 6; ++j) acc[j] = (f32x4){0.f, 0.f, 0.f, 0.f};

            bf16x8 aA[8], aB[8];
            #pragma unroll
            for (int q = 0; q < 8; ++q) aA[q] = ald16(ah + q * 32);
            #pragma unroll
            for (int q = 0; q < 8; ++q) aB[q] = ald16(ah + 256 + q * 32);
            #pragma unroll
            for (int q = 0; q < 8; ++q) {
                const int kk = q * 32;
                #pragma unroll
                for (int j = 0; j < 6; ++j)
                    acc[j] = MFMA16(aA[q], *(const bf16x8*)(wb[j] + kk), acc[j]);
            }
            #pragma unroll
            for (int q = 0; q < 8; ++q) aA[q] = ald16(ah + 512 + q * 32);
            #pragma unroll
            for (int q = 0; q < 8; ++q) {
                const int kk = 256 + q * 32;
                #pragma unroll
                for (int j = 0; j < 6; ++j)
                    acc[j] = MFMA16(aB[q], *(const bf16x8*)(wb[j] + kk), acc[j]);
            }
            #pragma unroll
            for (int q = 0; q < 8; ++q) aB[q] = ald16(ah + 768 + q * 32);
            #pragma unroll
            for (int q = 0; q < 8; ++q) {
                const int kk = 512 + q * 32;
                #pragma unroll
                for (int j = 0; j < 6; ++j)
                    acc[j] = MFMA16(aA[q], *(const bf16x8*)(wb[j] + kk), acc[j]);
            }
            #pragma unroll
            for (int q = 0; q < 8; ++q) {
                const int kk = 768 + q * 32;
                #pragma unroll
                for (int j = 0; j < 6; ++j)
                    acc[j] = MFMA16(aB[q], *(const bf16x8*)(wb[j] + kk), acc[j]);
            }

            if (role == 0) {
                // gi0: K=32 input matmul (R,Z folded into acc; N separate)
                f32x4 gn[2];
                gn[0] = (f32x4){0.f, 0.f, 0.f, 0.f}; gn[1] = gn[0];
                {
                    const short* x = enc ? xencbf : decinbf;
                    const int xs = enc ? TENC * 32 : TDEC * 32;
                    const short* wih0 = enc ? wih0e : wih0d;
                    bf16x8 ax = *(const bf16x8*)(x + (size_t)(b0 + lr) * xs + t * 32 + kg * 8);
                    #pragma unroll
                    for (int cs = 0; cs < 2; ++cs) {
                        bf16x8 br_ = *(const bf16x8*)(wih0 + (size_t)(i0 + cs * 16 + lr) * 32 + kg * 8);
                        bf16x8 bz_ = *(const bf16x8*)(wih0 + (size_t)(H + i0 + cs * 16 + lr) * 32 + kg * 8);
                        bf16x8 bn_ = *(const bf16x8*)(wih0 + (size_t)(2 * H + i0 + cs * 16 + lr) * 32 + kg * 8);
                        acc[cs * 3 + 0] = MFMA16(ax, br_, acc[cs * 3 + 0]);
                        acc[cs * 3 + 1] = MFMA16(ax, bz_, acc[cs * 3 + 1]);
                        gn[cs] = MFMA16(ax, bn_, gn[cs]);
                    }
                }
                const float* hfo = pp0 + (size_t)rds * HS;
                float*       hfn = pp0 + (size_t)(t & 1) * HS;
                short*       hbn = y0r + (size_t)(t & 1) * HS;
                #pragma unroll
                for (int cs = 0; cs < 2; ++cs) {
                    const int col = i0 + cs * 16 + lr;
                    #pragma unroll
                    for (int r = 0; r < 4; ++r) {
                        int row = b0 + kg * 4 + r;
                        float vr = sigmoidf_(acc[cs * 3 + 0][r] + bR[ph][cs]);
                        float vz = sigmoidf_(acc[cs * 3 + 1][r] + bZ[ph][cs]);
                        float vn = tanhf(gn[cs][r] + bGN[ph][cs] + vr * (acc[cs * 3 + 2][r] + bHN[ph][cs]));
                        float ho = hfo[(size_t)row * H + col];
                        float hn = (1.0f - vz) * vn + vz * ho;
                        hfn[(size_t)row * H + col] = hn;
                        unsigned myb = (unsigned)(unsigned short)f2bf_rne(hn);
                        unsigned ov  = __shfl_xor(myb, 1);
                        if (!(lane & 1))
                            __hip_atomic_store((unsigned*)(hbn + (size_t)row * H + col),
                                               myb | (ov << 16), __ATOMIC_RELAXED,
                                               __HIP_MEMORY_SCOPE_AGENT);
                    }
                }
            } else if (role == 1) {
                float* gio = gibuf + (size_t)(t & 1) * GIS;   // [gate][col][row]
                #pragma unroll
                for (int cs = 0; cs < 2; ++cs) {
                    const int col = i0 + cs * 16 + lr;
                    #pragma unroll
                    for (int g = 0; g < 3; ++g)
                        ast16f(&gio[((size_t)g * H + col) * BB + b0 + kg * 4], acc[cs * 3 + g]);
                }
            } else {
                const float* gii = gibuf + (size_t)(t & 1) * GIS;
                const float* hfo = (t == 0) ? (pp1 + HS)
                                 : (enc ? (pp1 + (size_t)((t - 1) & 1) * HS)
                                        : (y1 + (size_t)(t - 1) * HS));
                float* hfn = enc ? (pp1 + (size_t)(t & 1) * HS) : (y1 + (size_t)t * HS);
                short* hbn = hbf1 + (size_t)(t & 1) * HS;
                #pragma unroll
                for (int cs = 0; cs < 2; ++cs) {
                    const int col = i0 + cs * 16 + lr;
                    f32x4 gR = ald16f(&gii[((size_t)0 * H + col) * BB + b0 + kg * 4]);
                    f32x4 gZ = ald16f(&gii[((size_t)1 * H + col) * BB + b0 + kg * 4]);
                    f32x4 gN = ald16f(&gii[((size_t)2 * H + col) * BB + b0 + kg * 4]);
                    #pragma unroll
                    for (int r = 0; r < 4; ++r) {
                        int row = b0 + kg * 4 + r;
                        float vr = sigmoidf_(acc[cs * 3 + 0][r] + gR[r] + bR[ph][cs]);
                        float vz = sigmoidf_(acc[cs * 3 + 1][r] + gZ[r] + bZ[ph][cs]);
                        float vn = tanhf(gN[r] + bGN[ph][cs] + vr * (acc[cs * 3 + 2][r] + bHN[ph][cs]));
                        float ho = hfo[(size_t)row * H + col];
                        float hn = (1.0f - vz) * vn + vz * ho;
                        hfn[(size_t)row * H + col] = hn;
                        unsigned myb = (unsigned)(unsigned short)f2bf_rne(hn);
                        unsigned ov  = __shfl_xor(myb, 1);
                        if (!(lane & 1))
                            __hip_atomic_store((unsigned*)(hbn + (size_t)row * H + col),
                                               myb | (ov << 16), __ATOMIC_RELAXED,
                                               __HIP_MEMORY_SCOPE_AGENT);
                    }
                }
            }
        }

        // ---- hierarchical device barrier (no fences, no hot lines) ----
        asm volatile("s_waitcnt vmcnt(0)" ::: "memory");
        __syncthreads();
        const unsigned tgt = (unsigned)(u + 1);
        if (bid == 0) {
            if (w == 0) {
                if (lane == 0)
                    __hip_atomic_fetch_add(&barr[0], 1u, __ATOMIC_RELAXED,
                                           __HIP_MEMORY_SCOPE_AGENT);
                for (;;) {
                    unsigned v = (lane < 8)
                        ? __hip_atomic_load(&barr[lane * 32], __ATOMIC_RELAXED,
                                            __HIP_MEMORY_SCOPE_AGENT) : 0u;
                    bool ok = (lane >= 8) || (v >= tgt * 12u);
                    if (__all(ok)) break;
                    __builtin_amdgcn_s_sleep(4);
                }
                if (lane < 8)
                    __hip_atomic_store(&rel[lane * 32], tgt, __ATOMIC_RELAXED,
                                       __HIP_MEMORY_SCOPE_AGENT);
            }
        } else if (tid == 0) {
            __hip_atomic_fetch_add(&barr[(bid & 7) * 32], 1u, __ATOMIC_RELAXED,
                                   __HIP_MEMORY_SCOPE_AGENT);
            while (__hip_atomic_load(&rel[(bid & 7) * 32], __ATOMIC_RELAXED,
                                     __HIP_MEMORY_SCOPE_AGENT) < tgt)
                __builtin_amdgcn_s_sleep(8);
        }
        __syncthreads();
    }
}

// out[b][t][o] = sum_h y1[t][b][h] * W[o][h] + bias[o]   (pure fp32)
__global__ __launch_bounds__(256) void k_proj(const float* __restrict__ y1,
                                              const float* __restrict__ W,
                                              const float* __restrict__ bias,
                                              float* __restrict__ out) {
    int idx = blockIdx.x * 256 + threadIdx.x;
    if (idx >= TDEC * BB * 32) return;
    int o = idx & 31;
    int rt = idx >> 5;        // t*BB + b
    int t = rt >> 7;
    int b = rt & (BB - 1);
    const float4* yr = (const float4*)(y1 + (size_t)rt * H);
    const float4* wr = (const float4*)(W + (size_t)o * H);
    float s = 0.f;
    #pragma unroll 4
    for (int k = 0; k < H / 4; ++k) {
        float4 a = yr[k], w = wr[k];
        s += a.x * w.x + a.y * w.y + a.z * w.z + a.w * w.w;
    }
    out[(size_t)b * TDEC * 32 + (size_t)t * 32 + o] = s + bias[o];
}

extern "C" void kernel_launch(void* const* d_in, const int* in_sizes, int n_in,
                              void* d_out, int out_size, void* d_ws, size_t ws_size,
                              hipStream_t stream) {
    const float* x_enc = (const float*)d_in[0];
    const float* x_dec = (const float*)d_in[2];
    const float* eWih0 = (const float*)d_in[4];
    const float* eWhh0 = (const float*)d_in[5];
    const float* ebih0 = (const float*)d_in[6];
    const float* ebhh0 = (const float*)d_in[7];
    const float* eWih1 = (const float*)d_in[8];
    const float* eWhh1 = (const float*)d_in[9];
    const float* ebih1 = (const float*)d_in[10];
    const float* ebhh1 = (const float*)d_in[11];
    const float* dWih0 = (const float*)d_in[12];
    const float* dWhh0 = (const float*)d_in[13];
    const float* dbih0 = (const float*)d_in[14];
    const float* dbhh0 = (const float*)d_in[15];
    const float* dWih1 = (const float*)d_in[16];
    const float* dWhh1 = (const float*)d_in[17];
    const float* dbih1 = (const float*)d_in[18];
    const float* dbhh1 = (const float*)d_in[19];
    const float* outW  = (const float*)d_in[20];
    const float* outb  = (const float*)d_in[21];
    float* out = (float*)d_out;

    char* ws = (char*)d_ws;
    size_t off = 0;
    auto alloc = [&](size_t bytes) -> void* {
        void* p = ws + off;
        off += (bytes + 255) & ~(size_t)255;
        return p;
    };
    const size_t HS = (size_t)BB * H;
    short* wih0e  = (short*)alloc((size_t)G * 32 * 2);
    short* whh0e  = (short*)alloc((size_t)G * H * 2);
    short* wih1e  = (short*)alloc((size_t)G * H * 2);
    short* whh1e  = (short*)alloc((size_t)G * H * 2);
    short* wih0d  = (short*)alloc((size_t)G * 32 * 2);
    short* whh0d  = (short*)alloc((size_t)G * H * 2);
    short* wih1d  = (short*)alloc((size_t)G * H * 2);
    short* whh1d  = (short*)alloc((size_t)G * H * 2);
    short* xencbf = (short*)alloc((size_t)BB * TENC * 32 * 2);
    short* decinbf= (short*)alloc((size_t)BB * TDEC * 32 * 2);
    short* y0r    = (short*)alloc(2 * HS * 2);
    float* pp0    = (float*)alloc(2 * HS * 4);
    short* hbf1   = (short*)alloc(2 * HS * 2);
    float* pp1    = (float*)alloc(2 * HS * 4);
    float* gibuf  = (float*)alloc(2 * 3 * HS * 4);
    float* y1     = (float*)alloc((size_t)TDEC * HS * 4);
    unsigned* barr= (unsigned*)alloc(8 * 32 * 4);
    unsigned* rel = (unsigned*)alloc(8 * 32 * 4);
    (void)ws_size; (void)in_sizes; (void)n_in; (void)out_size;

    hipMemsetAsync(y0r, 0, 2 * HS * 2, stream);
    hipMemsetAsync(pp0, 0, 2 * HS * 4, stream);
    hipMemsetAsync(hbf1, 0, 2 * HS * 2, stream);
    hipMemsetAsync(pp1, 0, 2 * HS * 4, stream);
    hipMemsetAsync(barr, 0, 8 * 32 * 4, stream);
    hipMemsetAsync(rel, 0, 8 * 32 * 4, stream);

    auto cvt = [&](const float* src, short* dst, int n) {
        int blocks = (n + 255) / 256;
        if (blocks > 2048) blocks = 2048;
        k_f2bf<<<dim3(blocks), dim3(256), 0, stream>>>(src, dst, n);
    };
    cvt(eWih0, wih0e, G * 32);
    cvt(eWhh0, whh0e, G * H);
    cvt(eWih1, wih1e, G * H);
    cvt(eWhh1, whh1e, G * H);
    cvt(dWih0, wih0d, G * 32);
    cvt(dWhh0, whh0d, G * H);
    cvt(dWih1, wih1d, G * H);
    cvt(dWhh1, whh1d, G * H);
    cvt(x_enc, xencbf, BB * TENC * 32);
    k_build_decin<<<dim3((BB * TDEC * 32 + 255) / 256), dim3(256), 0, stream>>>(
        x_enc, x_dec, decinbf);

    k_persist<<<dim3(NBLK), dim3(512), 0, stream>>>(
        xencbf, decinbf,
        wih0e, whh0e, ebih0, ebhh0, wih1e, whh1e, ebih1, ebhh1,
        wih0d, whh0d, dbih0, dbhh0, wih1d, whh1d, dbih1, dbhh1,
        y0r, pp0, hbf1, pp1, gibuf, y1, barr, rel);

    k_proj<<<dim3((TDEC * BB * 32 + 255) / 256), dim3(256), 0, stream>>>(
        y1, outW, outb, out);
}

// Round 9
// 16257.048 us; speedup vs baseline: 1.1604x; 1.1604x over previous
//
#include <hip/hip_runtime.h>
#include <hip/hip_bf16.h>

// Seq2seq GRU (2-layer enc T=192, 2-layer dec T=96), B=128, H=1024.
// Round 9: launch-per-step (proven-correct coherence regime), minimized
// grid: 96 wgs x 512 thr per step (3 roles {L0, gi1, L1} x 32 i-tiles of
// 32 cols; 8 waves = 8 m-tiles of 16 rows; full K per wave, no LDS).
// Plain cached loads (full-rate streaming). 3-stage diagonal pipeline,
// 292 step launches. Fused prologue (1 memset + 2 prep kernels).
// bf16 MFMA (fp32 accum), fp32 master hidden state, fp32 projection.

#define H 1024
#define G 3072
#define BB 128
#define TENC 192
#define TDEC 96
#define NSTEP (TENC + 2 + TDEC + 2)   /* 194 + 98 = 292 */

typedef __attribute__((ext_vector_type(4))) float f32x4;
typedef __attribute__((ext_vector_type(8))) short bf16x8;

#define MFMA16(a, b, c) __builtin_amdgcn_mfma_f32_16x16x32_bf16(a, b, c, 0, 0, 0)

__device__ __forceinline__ float sigmoidf_(float x) {
    return 1.0f / (1.0f + __expf(-x));
}

__device__ __forceinline__ short f2bf_rne(float f) {
    union { float f; unsigned u; } v; v.f = f;
    unsigned r = v.u + 0x7fffu + ((v.u >> 16) & 1u);
    return (short)(r >> 16);
}

// Fused conversion of all 8 weight tensors into one contiguous bf16 arena.
// dst layout: [wih0e | whh0e | wih1e | whh1e | wih0d | whh0d | wih1d | whh1d]
__global__ __launch_bounds__(256) void k_cvt_all(
    const float* __restrict__ s0, const float* __restrict__ s1,
    const float* __restrict__ s2, const float* __restrict__ s3,
    const float* __restrict__ s4, const float* __restrict__ s5,
    const float* __restrict__ s6, const float* __restrict__ s7,
    short* __restrict__ dst)
{
    const int N0 = G * 32, NB = G * H;
    const int b0 = N0, b1 = b0 + NB, b2 = b1 + NB, b3 = b2 + NB;
    const int b4 = b3 + N0, b5 = b4 + NB, b6 = b5 + NB, b7 = b6 + NB;
    for (int i = blockIdx.x * 256 + threadIdx.x; i < b7; i += gridDim.x * 256) {
        float v;
        if      (i < b0) v = s0[i];
        else if (i < b1) v = s1[i - b0];
        else if (i < b2) v = s2[i - b1];
        else if (i < b3) v = s3[i - b2];
        else if (i < b4) v = s4[i - b3];
        else if (i < b5) v = s5[i - b4];
        else if (i < b6) v = s6[i - b5];
        else             v = s7[i - b6];
        dst[i] = f2bf_rne(v);
    }
}

// Fused input prep: x_enc -> bf16, and dec_in build (-> bf16).
__global__ __launch_bounds__(256) void k_xprep(const float* __restrict__ x_enc,
                                               const float* __restrict__ x_dec,
                                               short* __restrict__ xencbf,
                                               short* __restrict__ decinbf)
{
    const int NE = BB * TENC * 32, ND = BB * TDEC * 32;
    for (int i = blockIdx.x * 256 + threadIdx.x; i < NE + ND; i += gridDim.x * 256) {
        if (i < NE) {
            xencbf[i] = f2bf_rne(x_enc[i]);
        } else {
            int j = i - NE;
            int c = j & 31;
            int t = (j >> 5) % TDEC;
            int b = j / (TDEC * 32);
            float v = (t == 0) ? x_enc[(size_t)b * TENC * 32 + 191 * 32 + c]
                               : x_dec[(size_t)b * TDEC * 32 + (t - 1) * 32 + c];
            decinbf[j] = f2bf_rne(v);
        }
    }
}

// One diagonal pipeline step. 96 blocks x 512 thr.
// role = bid>>5: 0 = L0[s], 1 = gi1[s-1], 2 = L1[s-2]. i0 = (bid&31)*32.
// Wave w = m-tile (16 rows). Full K per wave. Ring: state at time t -> slot t&1.
__global__ __launch_bounds__(512) void k_step(
    int u,
    const short* __restrict__ xencbf, const short* __restrict__ decinbf,
    const short* __restrict__ wih0e, const short* __restrict__ whh0e,
    const float* __restrict__ ebih0, const float* __restrict__ ebhh0,
    const short* __restrict__ wih1e, const short* __restrict__ whh1e,
    const float* __restrict__ ebih1, const float* __restrict__ ebhh1,
    const short* __restrict__ wih0d, const short* __restrict__ whh0d,
    const float* __restrict__ dbih0, const float* __restrict__ dbhh0,
    const short* __restrict__ wih1d, const short* __restrict__ whh1d,
    const float* __restrict__ dbih1, const float* __restrict__ dbhh1,
    short* __restrict__ y0r, float* __restrict__ pp0,
    short* __restrict__ hbf1, float* __restrict__ pp1,
    float* __restrict__ gibuf, float* __restrict__ y1)
{
    const int tid  = threadIdx.x;
    const int w    = tid >> 6;
    const int lane = tid & 63;
    const int lr   = lane & 15;
    const int kg   = lane >> 4;
    const int bid  = blockIdx.x;
    const int role = bid >> 5;
    const int i0   = (bid & 31) * 32;
    const int b0   = w * 16;
    const size_t HS  = (size_t)BB * H;
    const size_t GIS = (size_t)3 * BB * H;

    const bool enc = (u < TENC + 2);
    const int s = enc ? u : (u - (TENC + 2));
    const int T = enc ? TENC : TDEC;
    const int t = s - role;
    if (t < 0 || t >= T) return;

    const int rds = (t == 0) ? 1 : ((t - 1) & 1);
    const short* abase = (role == 0) ? (y0r + (size_t)rds * HS)
                       : (role == 1) ? (y0r + (size_t)(t & 1) * HS)
                                     : (hbf1 + (size_t)rds * HS);
    const short* ah = abase + ((size_t)(b0 + lr) << 10) + kg * 8;
    const short* wsel = (role == 0) ? (enc ? whh0e : whh0d)
                      : (role == 1) ? (enc ? wih1e : wih1d)
                                    : (enc ? whh1e : whh1d);
    const short* wb[6];
    #pragma unroll
    for (int cs = 0; cs < 2; ++cs)
        #pragma unroll
        for (int g = 0; g < 3; ++g)
            wb[cs * 3 + g] = wsel + ((size_t)(g * H + i0 + cs * 16 + lr) << 10) + kg * 8;

    f32x4 acc[6];
    #pragma unroll
    for (int j = 0; j < 6; ++j) acc[j] = (f32x4){0.f, 0.f, 0.f, 0.f};

    // K-loop: 4 quarters of 256, A double-buffered 8-deep, 6 MFMA streams
    bf16x8 aA[8], aB[8];
    #pragma unroll
    for (int q = 0; q < 8; ++q) aA[q] = *(const bf16x8*)(ah + q * 32);
    #pragma unroll
    for (int q = 0; q < 8; ++q) aB[q] = *(const bf16x8*)(ah + 256 + q * 32);
    #pragma unroll
    for (int q = 0; q < 8; ++q) {
        const int kk = q * 32;
        #pragma unroll
        for (int j = 0; j < 6; ++j)
            acc[j] = MFMA16(aA[q], *(const bf16x8*)(wb[j] + kk), acc[j]);
    }
    #pragma unroll
    for (int q = 0; q < 8; ++q) aA[q] = *(const bf16x8*)(ah + 512 + q * 32);
    #pragma unroll
    for (int q = 0; q < 8; ++q) {
        const int kk = 256 + q * 32;
        #pragma unroll
        for (int j = 0; j < 6; ++j)
            acc[j] = MFMA16(aB[q], *(const bf16x8*)(wb[j] + kk), acc[j]);
    }
    #pragma unroll
    for (int q = 0; q < 8; ++q) aB[q] = *(const bf16x8*)(ah + 768 + q * 32);
    #pragma unroll
    for (int q = 0; q < 8; ++q) {
        const int kk = 512 + q * 32;
        #pragma unroll
        for (int j = 0; j < 6; ++j)
            acc[j] = MFMA16(aA[q], *(const bf16x8*)(wb[j] + kk), acc[j]);
    }
    #pragma unroll
    for (int q = 0; q < 8; ++q) {
        const int kk = 768 + q * 32;
        #pragma unroll
        for (int j = 0; j < 6; ++j)
            acc[j] = MFMA16(aB[q], *(const bf16x8*)(wb[j] + kk), acc[j]);
    }

    if (role == 0) {
        // gi0: K=32 input matmul (R,Z folded into acc; N-gate separate)
        f32x4 gn[2];
        gn[0] = (f32x4){0.f, 0.f, 0.f, 0.f}; gn[1] = gn[0];
        {
            const short* x = enc ? xencbf : decinbf;
            const int xs = enc ? TENC * 32 : TDEC * 32;
            const short* wih0 = enc ? wih0e : wih0d;
            bf16x8 ax = *(const bf16x8*)(x + (size_t)(b0 + lr) * xs + t * 32 + kg * 8);
            #pragma unroll
            for (int cs = 0; cs < 2; ++cs) {
                bf16x8 br_ = *(const bf16x8*)(wih0 + (size_t)(i0 + cs * 16 + lr) * 32 + kg * 8);
                bf16x8 bz_ = *(const bf16x8*)(wih0 + (size_t)(H + i0 + cs * 16 + lr) * 32 + kg * 8);
                bf16x8 bn_ = *(const bf16x8*)(wih0 + (size_t)(2 * H + i0 + cs * 16 + lr) * 32 + kg * 8);
                acc[cs * 3 + 0] = MFMA16(ax, br_, acc[cs * 3 + 0]);
                acc[cs * 3 + 1] = MFMA16(ax, bz_, acc[cs * 3 + 1]);
                gn[cs] = MFMA16(ax, bn_, gn[cs]);
            }
        }
        const float* bi = enc ? ebih0 : dbih0;
        const float* bh = enc ? ebhh0 : dbhh0;
        const float* hfo = pp0 + (size_t)rds * HS;
        float*       hfn = pp0 + (size_t)(t & 1) * HS;
        short*       hbn = y0r + (size_t)(t & 1) * HS;
        #pragma unroll
        for (int cs = 0; cs < 2; ++cs) {
            const int col = i0 + cs * 16 + lr;
            const float bR  = bi[col] + bh[col];
            const float bZ  = bi[H + col] + bh[H + col];
            const float bGN = bi[2 * H + col];
            const float bHN = bh[2 * H + col];
            #pragma unroll
            for (int r = 0; r < 4; ++r) {
                int row = b0 + kg * 4 + r;
                float vr = sigmoidf_(acc[cs * 3 + 0][r] + bR);
                float vz = sigmoidf_(acc[cs * 3 + 1][r] + bZ);
                float vn = tanhf(gn[cs][r] + bGN + vr * (acc[cs * 3 + 2][r] + bHN));
                float ho = hfo[(size_t)row * H + col];
                float hn = (1.0f - vz) * vn + vz * ho;
                hfn[(size_t)row * H + col] = hn;
                unsigned myb = (unsigned)(unsigned short)f2bf_rne(hn);
                unsigned ov  = __shfl_xor(myb, 1);
                if (!(lane & 1))
                    *(unsigned*)(hbn + (size_t)row * H + col) = myb | (ov << 16);
            }
        }
    } else if (role == 1) {
        float* gio = gibuf + (size_t)(t & 1) * GIS;   // [gate][col][row]
        #pragma unroll
        for (int cs = 0; cs < 2; ++cs) {
            const int col = i0 + cs * 16 + lr;
            #pragma unroll
            for (int g = 0; g < 3; ++g)
                *(f32x4*)(&gio[((size_t)g * H + col) * BB + b0 + kg * 4]) = acc[cs * 3 + g];
        }
    } else {
        const float* gii = gibuf + (size_t)(t & 1) * GIS;
        const float* bi = enc ? ebih1 : dbih1;
        const float* bh = enc ? ebhh1 : dbhh1;
        const float* hfo = (t == 0) ? (pp1 + HS)
                         : (enc ? (pp1 + (size_t)((t - 1) & 1) * HS)
                                : (y1 + (size_t)(t - 1) * HS));
        float* hfn = enc ? (pp1 + (size_t)(t & 1) * HS) : (y1 + (size_t)t * HS);
        short* hbn = hbf1 + (size_t)(t & 1) * HS;
        #pragma unroll
        for (int cs = 0; cs < 2; ++cs) {
            const int col = i0 + cs * 16 + lr;
            const float bR  = bi[col] + bh[col];
            const float bZ  = bi[H + col] + bh[H + col];
            const float bGN = bi[2 * H + col];
            const float bHN = bh[2 * H + col];
            f32x4 gR = *(const f32x4*)(&gii[((size_t)0 * H + col) * BB + b0 + kg * 4]);
            f32x4 gZ = *(const f32x4*)(&gii[((size_t)1 * H + col) * BB + b0 + kg * 4]);
            f32x4 gN = *(const f32x4*)(&gii[((size_t)2 * H + col) * BB + b0 + kg * 4]);
            #pragma unroll
            for (int r = 0; r < 4; ++r) {
                int row = b0 + kg * 4 + r;
                float vr = sigmoidf_(acc[cs * 3 + 0][r] + gR[r] + bR);
                float vz = sigmoidf_(acc[cs * 3 + 1][r] + gZ[r] + bZ);
                float vn = tanhf(gN[r] + bGN + vr * (acc[cs * 3 + 2][r] + bHN));
                float ho = hfo[(size_t)row * H + col];
                float hn = (1.0f - vz) * vn + vz * ho;
                hfn[(size_t)row * H + col] = hn;
                unsigned myb = (unsigned)(unsigned short)f2bf_rne(hn);
                unsigned ov  = __shfl_xor(myb, 1);
                if (!(lane & 1))
                    *(unsigned*)(hbn + (size_t)row * H + col) = myb | (ov << 16);
            }
        }
    }
}

// out[b][t][o] = sum_h y1[t][b][h] * W[o][h] + bias[o]   (pure fp32)
__global__ __launch_bounds__(256) void k_proj(const float* __restrict__ y1,
                                              const float* __restrict__ W,
                                              const float* __restrict__ bias,
                                              float* __restrict__ out) {
    int idx = blockIdx.x * 256 + threadIdx.x;
    if (idx >= TDEC * BB * 32) return;
    int o = idx & 31;
    int rt = idx >> 5;        // t*BB + b
    int t = rt >> 7;
    int b = rt & (BB - 1);
    const float4* yr = (const float4*)(y1 + (size_t)rt * H);
    const float4* wr = (const float4*)(W + (size_t)o * H);
    float s = 0.f;
    #pragma unroll 4
    for (int k = 0; k < H / 4; ++k) {
        float4 a = yr[k], w = wr[k];
        s += a.x * w.x + a.y * w.y + a.z * w.z + a.w * w.w;
    }
    out[(size_t)b * TDEC * 32 + (size_t)t * 32 + o] = s + bias[o];
}

extern "C" void kernel_launch(void* const* d_in, const int* in_sizes, int n_in,
                              void* d_out, int out_size, void* d_ws, size_t ws_size,
                              hipStream_t stream) {
    const float* x_enc = (const float*)d_in[0];
    const float* x_dec = (const float*)d_in[2];
    const float* eWih0 = (const float*)d_in[4];
    const float* eWhh0 = (const float*)d_in[5];
    const float* ebih0 = (const float*)d_in[6];
    const float* ebhh0 = (const float*)d_in[7];
    const float* eWih1 = (const float*)d_in[8];
    const float* eWhh1 = (const float*)d_in[9];
    const float* ebih1 = (const float*)d_in[10];
    const float* ebhh1 = (const float*)d_in[11];
    const float* dWih0 = (const float*)d_in[12];
    const float* dWhh0 = (const float*)d_in[13];
    const float* dbih0 = (const float*)d_in[14];
    const float* dbhh0 = (const float*)d_in[15];
    const float* dWih1 = (const float*)d_in[16];
    const float* dWhh1 = (const float*)d_in[17];
    const float* dbih1 = (const float*)d_in[18];
    const float* dbhh1 = (const float*)d_in[19];
    const float* outW  = (const float*)d_in[20];
    const float* outb  = (const float*)d_in[21];
    float* out = (float*)d_out;

    char* ws = (char*)d_ws;
    size_t off = 0;
    auto alloc = [&](size_t bytes) -> void* {
        void* p = ws + off;
        off += (bytes + 255) & ~(size_t)255;
        return p;
    };
    const size_t HS = (size_t)BB * H;
    // weight arena: 8 tensors contiguous (sizes are multiples of 256 B)
    short* warena = (short*)alloc(((size_t)2 * G * 32 + (size_t)6 * G * H) * 2);
    short* wih0e  = warena;
    short* whh0e  = wih0e + (size_t)G * 32;
    short* wih1e  = whh0e + (size_t)G * H;
    short* whh1e  = wih1e + (size_t)G * H;
    short* wih0d  = whh1e + (size_t)G * H;
    short* whh0d  = wih0d + (size_t)G * 32;
    short* wih1d  = whh0d + (size_t)G * H;
    short* whh1d  = wih1d + (size_t)G * H;
    short* xencbf = (short*)alloc((size_t)BB * TENC * 32 * 2);
    short* decinbf= (short*)alloc((size_t)BB * TDEC * 32 * 2);
    // zero arena: state rings contiguous -> one memset
    char*  zarena = (char*)alloc(2 * HS * 2 + 2 * HS * 4 + 2 * HS * 2 + 2 * HS * 4);
    short* y0r    = (short*)zarena;
    float* pp0    = (float*)(zarena + 2 * HS * 2);
    short* hbf1   = (short*)(zarena + 2 * HS * 2 + 2 * HS * 4);
    float* pp1    = (float*)(zarena + 2 * HS * 2 + 2 * HS * 4 + 2 * HS * 2);
    float* gibuf  = (float*)alloc(2 * 3 * HS * 4);
    float* y1     = (float*)alloc((size_t)TDEC * HS * 4);
    (void)ws_size; (void)in_sizes; (void)n_in; (void)out_size;

    hipMemsetAsync(zarena, 0, 2 * HS * 2 + 2 * HS * 4 + 2 * HS * 2 + 2 * HS * 4, stream);

    k_cvt_all<<<dim3(2048), dim3(256), 0, stream>>>(
        eWih0, eWhh0, eWih1, eWhh1, dWih0, dWhh0, dWih1, dWhh1, warena);
    k_xprep<<<dim3(1024), dim3(256), 0, stream>>>(x_enc, x_dec, xencbf, decinbf);

    for (int u = 0; u < NSTEP; ++u)
        k_step<<<dim3(96), dim3(512), 0, stream>>>(u,
            xencbf, decinbf,
            wih0e, whh0e, ebih0, ebhh0, wih1e, whh1e, ebih1, ebhh1,
            wih0d, whh0d, dbih0, dbhh0, wih1d, whh1d, dbih1, dbhh1,
            y0r, pp0, hbf1, pp1, gibuf, y1);

    k_proj<<<dim3((TDEC * BB * 32 + 255) / 256), dim3(256), 0, stream>>>(
        y1, outW, outb, out);
}